// Round 16
// baseline (67.893 us; speedup 1.0000x reference)
//
#include <hip/hip_runtime.h>
#include <hip/hip_bf16.h>

#define SEQL 4096
#define MROWS 32768
#define DMODEL 512
#define KFULL 1024

typedef __attribute__((ext_vector_type(8))) short bf16x8;
typedef __attribute__((ext_vector_type(4))) unsigned u32x4;
typedef __attribute__((ext_vector_type(4))) float f32x4;

__device__ __forceinline__ unsigned cvt_pk2(float a, float b) {
    unsigned r;
    asm("v_cvt_pk_bf16_f32 %0, %1, %2" : "=v"(r) : "v"(a), "v"(b));
    return r;
}

__device__ __forceinline__ float nonsat(float x) {
    float y = x;
    #pragma unroll
    for (int i = 0; i < 5; ++i) {
        float y2  = y * y;
        float num = __builtin_fmaf(y2 * y, 0.66666667f, x);
        y = num * __builtin_amdgcn_rcpf(y2 + 1.0f);
    }
    return y;
}

// W (512x1024 f32 [n][k]) -> fragment-tiled bf16:
// frag f = (k/32)*32 + (n/16); lane = ((k/8)&3)*16 + (n&15); elems k..k+7.
__global__ __launch_bounds__(256) void cvt_w(const float* __restrict__ W,
                                             short* __restrict__ Wbf) {
    int t8 = blockIdx.x * 256 + threadIdx.x;
    int n = t8 >> 7;
    int k = (t8 & 127) << 3;
    f32x4 lo = *(const f32x4*)(W + (size_t)n * KFULL + k);
    f32x4 hi = *(const f32x4*)(W + (size_t)n * KFULL + k + 4);
    u32x4 v;
    v[0] = cvt_pk2(lo[0], lo[1]); v[1] = cvt_pk2(lo[2], lo[3]);
    v[2] = cvt_pk2(hi[0], hi[1]); v[3] = cvt_pk2(hi[2], hi[3]);
    int f    = (k >> 5) * 32 + (n >> 4);
    int lane = ((k >> 3) & 3) * 16 + (n & 15);
    *(u32x4*)(Wbf + (size_t)f * 512 + lane * 8) = v;
}

// pe_gemm (swapped operands): P[l][n] = (pe @ W2^T)[l][n] + bias[n]
__global__ __launch_bounds__(256, 2) void pe_gemm(const float* __restrict__ pe,
                                                  const short* __restrict__ Wbf,
                                                  const float* __restrict__ bias,
                                                  float* __restrict__ P) {
    __shared__ short As[2][32 * 64];
    const int tid  = threadIdx.x;
    const int wn   = tid >> 6;
    const int lane = tid & 63;
    const int l4   = lane & 15;
    const int kg   = lane >> 4;
    const int l0   = blockIdx.x * 32;

    f32x4 acc[2][8];
    #pragma unroll
    for (int mi = 0; mi < 2; ++mi)
        #pragma unroll
        for (int t = 0; t < 8; ++t) acc[mi][t] = (f32x4){0.f,0.f,0.f,0.f};

    const int ar = tid >> 3;
    const int kc = (tid & 7) << 3;
    const int sw = (ar & 7) << 3;
    const int sb = ar * 64 + kc;
    const float* xp = pe + (size_t)(l0 + ar) * DMODEL + kc;

    {
        f32x4 a = *(const f32x4*)xp, b = *(const f32x4*)(xp + 4);
        u32x4 v;
        v[0] = cvt_pk2(a[0], a[1]); v[1] = cvt_pk2(a[2], a[3]);
        v[2] = cvt_pk2(b[0], b[1]); v[3] = cvt_pk2(b[2], b[3]);
        *(u32x4*)&As[0][sb ^ sw] = v;
    }
    f32x4 xa = *(const f32x4*)(xp + 64), xb = *(const f32x4*)(xp + 68);

    #pragma unroll
    for (int ks = 0; ks < 8; ++ks) {
        const int cur = ks & 1;
        __syncthreads();
        if (ks < 7) {
            u32x4 v;
            v[0] = cvt_pk2(xa[0], xa[1]); v[1] = cvt_pk2(xa[2], xa[3]);
            v[2] = cvt_pk2(xb[0], xb[1]); v[3] = cvt_pk2(xb[2], xb[3]);
            *(u32x4*)&As[cur ^ 1][sb ^ sw] = v;
        }
        if (ks < 6) {
            xa = *(const f32x4*)(xp + (ks + 2) * 64);
            xb = *(const f32x4*)(xp + (ks + 2) * 64 + 4);
        }
        #pragma unroll
        for (int ksub = 0; ksub < 2; ++ksub) {
            const short* bp = Wbf + (size_t)((16 + ks * 2 + ksub) * 32 + wn * 8) * 512 + lane * 8;
            bf16x8 aw[8];
            #pragma unroll
            for (int t = 0; t < 8; ++t) aw[t] = *(const bf16x8*)(bp + (size_t)t * 512);
            bf16x8 bx[2];
            #pragma unroll
            for (int mi = 0; mi < 2; ++mi) {
                int idx = ((mi * 16 + l4) * 64 + ksub * 32 + kg * 8) ^ ((l4 & 7) << 3);
                bx[mi] = *(const bf16x8*)&As[cur][idx];
            }
            __builtin_amdgcn_s_setprio(1);
            #pragma unroll
            for (int t = 0; t < 8; ++t)
                #pragma unroll
                for (int mi = 0; mi < 2; ++mi)
                    acc[mi][t] = __builtin_amdgcn_mfma_f32_16x16x32_bf16(aw[t], bx[mi], acc[mi][t], 0, 0, 0);
            __builtin_amdgcn_s_setprio(0);
        }
    }

    #pragma unroll
    for (int mi = 0; mi < 2; ++mi)
        #pragma unroll
        for (int t = 0; t < 8; ++t) {
            int n = wn * 128 + t * 16 + kg * 4;
            f32x4 b4 = *(const f32x4*)(bias + n);
            f32x4 v = acc[mi][t] + b4;
            *(f32x4*)(P + (size_t)(l0 + mi * 16 + l4) * DMODEL + n) = v;
        }
}

// main: out = nonsat(LN(x @ W1^T + P[m>>3]))
// 128 rows x 512 cols per block, 16 waves (2m x 8n), wave tile 64x64,
// acc[4][4] = 64 AGPR -> launch_bounds(1024,4) forces <=128 regs/wave
// -> 4 waves/SIMD (2x prior occupancy; the untested axis after r13's
// ablation showed a pure load->MFMA latency chain at 2 waves/SIMD).
// r15 skeleton otherwise: double-buffered LDS W (frag layout, flat copy)
// + x (frag layout, write-side permutation), 1 barrier/k-step.
__global__ __launch_bounds__(1024, 4) void main_fused(
    const float* __restrict__ x, const short* __restrict__ Wbf,
    const float* __restrict__ P, const float* __restrict__ gamma,
    const float* __restrict__ beta, float* __restrict__ out)
{
    __shared__ __align__(16) short Wl[2][16384];   // 64 KB
    __shared__ __align__(16) short As[2][4096];    // 16 KB
    __shared__ float P_lds[16 * 512];              // 32 KB
    __shared__ float GB[2][512];                   // 4 KB
    __shared__ float red[8][128][2];               // 8 KB   -> 124 KB total

    const int tid  = threadIdx.x;
    const int wid  = tid >> 6;
    const int wm   = wid >> 3;          // 0..1  (64-row m-group)
    const int wn   = wid & 7;           // 0..7  (64-col n-group)
    const int lane = tid & 63;
    const int l4   = lane & 15;
    const int kg   = lane >> 4;
    const int m0   = blockIdx.x * 128;
    const int l0   = m0 >> 3;

    f32x4 acc[4][4];   // rows wm*64+mi*16+l4 ; cols wn*64 + t*16 + kg*4 + j
    #pragma unroll
    for (int mi = 0; mi < 4; ++mi)
        #pragma unroll
        for (int t = 0; t < 4; ++t) acc[mi][t] = (f32x4){0.f,0.f,0.f,0.f};

    // x staging: thread -> row tid/8, 4 fp32 at k = (tid&7)*4 within k-step
    const int xrow = tid >> 3;
    const float* xp = x + (size_t)(m0 + xrow) * DMODEL + (tid & 7) * 4;
    // As frag-layout write (shorts): frag = row/16; lane = (k/8)*16 + row%16;
    // this thread holds half an 8-elem group: g=(tid&7)>>1, half=(tid&7)&1.
    const int as_adr = (xrow >> 4) * 512
                     + (((tid & 7) >> 1) * 16 + (xrow & 15)) * 8
                     + ((tid & 7) & 1) * 4;

    u32x4 wr0, wr1;
    f32x4 xr;

    #define LOADS(kf)  do {                                                 \
        const short* wg = Wbf + (size_t)(kf) * 16384 + tid * 8;             \
        wr0 = *(const u32x4*)(wg);                                          \
        wr1 = *(const u32x4*)(wg + 8192);                                   \
        xr  = *(const f32x4*)(xp + (kf) * 32);                              \
    } while (0)

    #define WRITES(b)  do {                                                 \
        *(u32x4*)&Wl[b][tid * 8]        = wr0;                              \
        *(u32x4*)&Wl[b][tid * 8 + 8192] = wr1;                              \
        uint2 v;                                                            \
        v.x = cvt_pk2(xr[0], xr[1]); v.y = cvt_pk2(xr[2], xr[3]);           \
        *(uint2*)&As[b][as_adr] = v;                                        \
    } while (0)

    LOADS(0);
    WRITES(0);
    LOADS(1);

    f32x4 pv[2], gb;

    #pragma unroll
    for (int kf = 0; kf < 16; ++kf) {
        const int cur = kf & 1;
        __syncthreads();
        if (kf < 15) WRITES(cur ^ 1);
        if (kf < 14) LOADS(kf + 2);
        if (kf == 13) {
            const float* Pg = P + (size_t)l0 * DMODEL;
            #pragma unroll
            for (int i = 0; i < 2; ++i) pv[i] = *(const f32x4*)(Pg + i * 4096 + tid * 4);
            if (tid < 256) {
                const float* gsrc = (tid < 128) ? (gamma + tid * 4) : (beta + (tid - 128) * 4);
                gb = *(const f32x4*)gsrc;
            }
        }
        bf16x8 aw[4];
        #pragma unroll
        for (int t = 0; t < 4; ++t)
            aw[t] = *(const bf16x8*)&Wl[cur][(wn * 4 + t) * 512 + lane * 8];
        bf16x8 bx[4];
        #pragma unroll
        for (int mi = 0; mi < 4; ++mi)
            bx[mi] = *(const bf16x8*)&As[cur][(wm * 4 + mi) * 512 + lane * 8];
        __builtin_amdgcn_s_setprio(1);
        #pragma unroll
        for (int t = 0; t < 4; ++t)
            #pragma unroll
            for (int mi = 0; mi < 4; ++mi)
                acc[mi][t] = __builtin_amdgcn_mfma_f32_16x16x32_bf16(aw[t], bx[mi], acc[mi][t], 0, 0, 0);
        __builtin_amdgcn_s_setprio(0);
    }
    #undef LOADS
    #undef WRITES

    // ---- stage P (flat, conflict-free) + gamma/beta to LDS ----
    #pragma unroll
    for (int i = 0; i < 2; ++i) *(f32x4*)&P_lds[i * 4096 + tid * 4] = pv[i];
    if (tid < 256) {
        if (tid < 128) *(f32x4*)&GB[0][tid * 4]         = gb;
        else           *(f32x4*)&GB[1][(tid - 128) * 4] = gb;
    }
    __syncthreads();

    // ---- add P (broadcast LDS reads) ----
    #pragma unroll
    for (int mi = 0; mi < 4; ++mi) {
        int lp = wm * 8 + mi * 2 + (l4 >> 3);
        #pragma unroll
        for (int t = 0; t < 4; ++t) {
            f32x4 p4 = *(const f32x4*)&P_lds[lp * 512 + wn * 64 + t * 16 + kg * 4];
            acc[mi][t] += p4;
        }
    }

    // ---- LN stats: in-register sums (per-wave 64 cols) + cross-wave red ----
    float S[4], Q[4];
    #pragma unroll
    for (int mi = 0; mi < 4; ++mi) {
        float s = 0.f, q = 0.f;
        #pragma unroll
        for (int t = 0; t < 4; ++t)
            #pragma unroll
            for (int j = 0; j < 4; ++j) {
                float v = acc[mi][t][j];
                s += v; q = __builtin_fmaf(v, v, q);
            }
        s += __shfl_xor(s, 16); q += __shfl_xor(q, 16);
        s += __shfl_xor(s, 32); q += __shfl_xor(q, 32);
        S[mi] = s; Q[mi] = q;
    }
    if (lane < 16) {
        #pragma unroll
        for (int mi = 0; mi < 4; ++mi) {
            red[wn][wm * 64 + mi * 16 + l4][0] = S[mi];
            red[wn][wm * 64 + mi * 16 + l4][1] = Q[mi];
        }
    }
    __syncthreads();

    // ---- normalize + nonsat + stores ----
    #pragma unroll
    for (int mi = 0; mi < 4; ++mi) {
        int r = wm * 64 + mi * 16 + l4;
        float Ss = 0.f, Qs = 0.f;
        #pragma unroll
        for (int w = 0; w < 8; ++w) { Ss += red[w][r][0]; Qs += red[w][r][1]; }
        float mean = Ss * (1.0f / 512.0f);
        float var  = Qs * (1.0f / 512.0f) - mean * mean;
        float rstd = rsqrtf(var + 1e-5f);
        float nmrs = -mean * rstd;
        float* orow = out + (size_t)(m0 + r) * DMODEL;
        #pragma unroll
        for (int t = 0; t < 4; ++t) {
            int n = wn * 64 + t * 16 + kg * 4;
            f32x4 g4 = *(const f32x4*)&GB[0][n];
            f32x4 b4 = *(const f32x4*)&GB[1][n];
            f32x4 o;
            #pragma unroll
            for (int j = 0; j < 4; ++j) {
                float z = __builtin_fmaf(acc[mi][t][j], rstd, nmrs);
                float v = __builtin_fmaf(z, g4[j], b4[j]);
                o[j] = nonsat(v);
            }
            *(f32x4*)(orow + n) = o;
        }
    }
}

// ---------- fallback (no workspace) ----------
__global__ __launch_bounds__(256) void fallback_fwd(
    const float* __restrict__ x, const float* __restrict__ Wf,
    const float* __restrict__ bias, const float* __restrict__ gamma,
    const float* __restrict__ beta, const float* __restrict__ pe,
    float* __restrict__ out)
{
    const int tid  = threadIdx.x;
    const int wave = tid >> 6;
    const int lane = tid & 63;
    const int lrow = lane & 15;
    const int kgrp = lane >> 4;
    const int n0   = wave * 128;
    const int m0   = blockIdx.x * 32;

    f32x4 acc[2][8];
    #pragma unroll
    for (int a = 0; a < 2; ++a)
        #pragma unroll
        for (int t = 0; t < 8; ++t) acc[a][t] = (f32x4){0.f,0.f,0.f,0.f};

    const int mA[2] = { m0 + lrow, m0 + 16 + lrow };
    for (int ks = 0; ks < 32; ++ks) {
        const int kb = ks * 32 + kgrp * 8;
        bf16x8 afrag[2];
        #pragma unroll
        for (int a = 0; a < 2; ++a) {
            const float* src = (kb < 512)
                ? (x  + (size_t)mA[a] * 512 + kb)
                : (pe + (size_t)(mA[a] >> 3) * 512 + (kb - 512));
            f32x4 lo = *(const f32x4*)src;
            f32x4 hi = *(const f32x4*)(src + 4);
            union { u32x4 u; bf16x8 s; } cv;
            cv.u[0] = cvt_pk2(lo[0], lo[1]); cv.u[1] = cvt_pk2(lo[2], lo[3]);
            cv.u[2] = cvt_pk2(hi[0], hi[1]); cv.u[3] = cvt_pk2(hi[2], hi[3]);
            afrag[a] = cv.s;
        }
        #pragma unroll
        for (int t = 0; t < 8; ++t) {
            const int n = n0 + t * 16 + lrow;
            const float* wsrc = Wf + (size_t)n * KFULL + kb;
            f32x4 lo = *(const f32x4*)wsrc;
            f32x4 hi = *(const f32x4*)(wsrc + 4);
            union { u32x4 u; bf16x8 s; } cv;
            cv.u[0] = cvt_pk2(lo[0], lo[1]); cv.u[1] = cvt_pk2(lo[2], lo[3]);
            cv.u[2] = cvt_pk2(hi[0], hi[1]); cv.u[3] = cvt_pk2(hi[2], hi[3]);
            acc[0][t] = __builtin_amdgcn_mfma_f32_16x16x32_bf16(afrag[0], cv.s, acc[0][t], 0, 0, 0);
            acc[1][t] = __builtin_amdgcn_mfma_f32_16x16x32_bf16(afrag[1], cv.s, acc[1][t], 0, 0, 0);
        }
    }
    __shared__ float red[4][32][2];
    float bcol[8], gcol[8], ecol[8];
    #pragma unroll
    for (int t = 0; t < 8; ++t) {
        const int n = n0 + t * 16 + lrow;
        bcol[t] = bias[n]; gcol[t] = gamma[n]; ecol[t] = beta[n];
    }
    #pragma unroll
    for (int a = 0; a < 2; ++a)
        #pragma unroll
        for (int t = 0; t < 8; ++t)
            #pragma unroll
            for (int j = 0; j < 4; ++j) acc[a][t][j] += bcol[t];
    float sm[2][4], sq[2][4];
    #pragma unroll
    for (int a = 0; a < 2; ++a)
        #pragma unroll
        for (int j = 0; j < 4; ++j) {
            float s = 0.f, q = 0.f;
            #pragma unroll
            for (int t = 0; t < 8; ++t) { float v = acc[a][t][j]; s += v; q += v * v; }
            #pragma unroll
            for (int msk = 1; msk <= 8; msk <<= 1) {
                s += __shfl_xor(s, msk, 64);
                q += __shfl_xor(q, msk, 64);
            }
            sm[a][j] = s; sq[a][j] = q;
        }
    if (lrow == 0) {
        #pragma unroll
        for (int a = 0; a < 2; ++a)
            #pragma unroll
            for (int j = 0; j < 4; ++j) {
                int r = a * 16 + kgrp * 4 + j;
                red[wave][r][0] = sm[a][j];
                red[wave][r][1] = sq[a][j];
            }
    }
    __syncthreads();
    #pragma unroll
    for (int a = 0; a < 2; ++a)
        #pragma unroll
        for (int j = 0; j < 4; ++j) {
            const int r = a * 16 + kgrp * 4 + j;
            float Ss = red[0][r][0] + red[1][r][0] + red[2][r][0] + red[3][r][0];
            float Qs = red[0][r][1] + red[1][r][1] + red[2][r][1] + red[3][r][1];
            float mean = Ss * (1.0f / 512.0f);
            float var  = Qs * (1.0f / 512.0f) - mean * mean;
            float rstd = rsqrtf(var + 1e-5f);
            const int m = m0 + a * 16 + kgrp * 4 + j;
            float* orow = out + (size_t)m * 512;
            #pragma unroll
            for (int t = 0; t < 8; ++t) {
                const int n = n0 + t * 16 + lrow;
                float v = (acc[a][t][j] - mean) * rstd * gcol[t] + ecol[t];
                orow[n] = nonsat(v);
            }
        }
}

extern "C" void kernel_launch(void* const* d_in, const int* in_sizes, int n_in,
                              void* d_out, int out_size, void* d_ws, size_t ws_size,
                              hipStream_t stream) {
    const float* x     = (const float*)d_in[0];
    const float* W     = (const float*)d_in[1];
    const float* bias  = (const float*)d_in[2];
    const float* gamma = (const float*)d_in[3];
    const float* beta  = (const float*)d_in[4];
    const float* pe    = (const float*)d_in[5];
    float* out = (float*)d_out;

    const size_t WBF_BYTES = (size_t)KFULL * DMODEL * sizeof(short);   // 1 MB
    const size_t P_BYTES   = (size_t)SEQL * DMODEL * sizeof(float);    // 8 MB

    if (ws_size >= WBF_BYTES + P_BYTES) {
        short* Wbf = (short*)d_ws;
        float* P   = (float*)((char*)d_ws + WBF_BYTES);
        cvt_w<<<dim3((DMODEL * KFULL) / (256 * 8)), dim3(256), 0, stream>>>(W, Wbf);
        pe_gemm<<<dim3(SEQL / 32), dim3(256), 0, stream>>>(pe, Wbf, bias, P);
        main_fused<<<dim3(MROWS / 128), dim3(1024), 0, stream>>>(x, Wbf, P, gamma, beta, out);
    } else {
        fallback_fwd<<<dim3(MROWS / 32), dim3(256), 0, stream>>>(x, W, bias, gamma, beta, pe, out);
    }
}

// Round 17
// 61.496 us; speedup vs baseline: 1.1040x; 1.1040x over previous
//
#include <hip/hip_runtime.h>
#include <hip/hip_bf16.h>

#define SEQL 4096
#define MROWS 32768
#define DMODEL 512
#define KFULL 1024

typedef __attribute__((ext_vector_type(8))) short bf16x8;
typedef __attribute__((ext_vector_type(4))) unsigned u32x4;
typedef __attribute__((ext_vector_type(4))) float f32x4;

__device__ __forceinline__ unsigned cvt_pk2(float a, float b) {
    unsigned r;
    asm("v_cvt_pk_bf16_f32 %0, %1, %2" : "=v"(r) : "v"(a), "v"(b));
    return r;
}

__device__ __forceinline__ float nonsat(float x) {
    float y = x;
    #pragma unroll
    for (int i = 0; i < 5; ++i) {
        float y2  = y * y;
        float num = __builtin_fmaf(y2 * y, 0.66666667f, x);
        y = num * __builtin_amdgcn_rcpf(y2 + 1.0f);
    }
    return y;
}

// async 16B global -> LDS (no VGPR round-trip; tracked by vmcnt)
__device__ __forceinline__ void gll16(const void* g, void* l) {
    __builtin_amdgcn_global_load_lds(
        (const __attribute__((address_space(1))) unsigned*)g,
        (__attribute__((address_space(3))) unsigned*)l, 16, 0, 0);
}

// W (512x1024 f32 [n][k]) -> fragment-tiled bf16:
// frag f = (k/32)*32 + (n/16); lane = ((k/8)&3)*16 + (n&15); elems k..k+7.
__global__ __launch_bounds__(256) void cvt_w(const float* __restrict__ W,
                                             short* __restrict__ Wbf) {
    int t8 = blockIdx.x * 256 + threadIdx.x;
    int n = t8 >> 7;
    int k = (t8 & 127) << 3;
    f32x4 lo = *(const f32x4*)(W + (size_t)n * KFULL + k);
    f32x4 hi = *(const f32x4*)(W + (size_t)n * KFULL + k + 4);
    u32x4 v;
    v[0] = cvt_pk2(lo[0], lo[1]); v[1] = cvt_pk2(lo[2], lo[3]);
    v[2] = cvt_pk2(hi[0], hi[1]); v[3] = cvt_pk2(hi[2], hi[3]);
    int f    = (k >> 5) * 32 + (n >> 4);
    int lane = ((k >> 3) & 3) * 16 + (n & 15);
    *(u32x4*)(Wbf + (size_t)f * 512 + lane * 8) = v;
}

// pe_gemm (swapped operands): P[l][n] = (pe @ W2^T)[l][n] + bias[n]
__global__ __launch_bounds__(256, 2) void pe_gemm(const float* __restrict__ pe,
                                                  const short* __restrict__ Wbf,
                                                  const float* __restrict__ bias,
                                                  float* __restrict__ P) {
    __shared__ short As[2][32 * 64];
    const int tid  = threadIdx.x;
    const int wn   = tid >> 6;
    const int lane = tid & 63;
    const int l4   = lane & 15;
    const int kg   = lane >> 4;
    const int l0   = blockIdx.x * 32;

    f32x4 acc[2][8];
    #pragma unroll
    for (int mi = 0; mi < 2; ++mi)
        #pragma unroll
        for (int t = 0; t < 8; ++t) acc[mi][t] = (f32x4){0.f,0.f,0.f,0.f};

    const int ar = tid >> 3;
    const int kc = (tid & 7) << 3;
    const int sw = (ar & 7) << 3;
    const int sb = ar * 64 + kc;
    const float* xp = pe + (size_t)(l0 + ar) * DMODEL + kc;

    {
        f32x4 a = *(const f32x4*)xp, b = *(const f32x4*)(xp + 4);
        u32x4 v;
        v[0] = cvt_pk2(a[0], a[1]); v[1] = cvt_pk2(a[2], a[3]);
        v[2] = cvt_pk2(b[0], b[1]); v[3] = cvt_pk2(b[2], b[3]);
        *(u32x4*)&As[0][sb ^ sw] = v;
    }
    f32x4 xa = *(const f32x4*)(xp + 64), xb = *(const f32x4*)(xp + 68);

    #pragma unroll
    for (int ks = 0; ks < 8; ++ks) {
        const int cur = ks & 1;
        __syncthreads();
        if (ks < 7) {
            u32x4 v;
            v[0] = cvt_pk2(xa[0], xa[1]); v[1] = cvt_pk2(xa[2], xa[3]);
            v[2] = cvt_pk2(xb[0], xb[1]); v[3] = cvt_pk2(xb[2], xb[3]);
            *(u32x4*)&As[cur ^ 1][sb ^ sw] = v;
        }
        if (ks < 6) {
            xa = *(const f32x4*)(xp + (ks + 2) * 64);
            xb = *(const f32x4*)(xp + (ks + 2) * 64 + 4);
        }
        #pragma unroll
        for (int ksub = 0; ksub < 2; ++ksub) {
            const short* bp = Wbf + (size_t)((16 + ks * 2 + ksub) * 32 + wn * 8) * 512 + lane * 8;
            bf16x8 aw[8];
            #pragma unroll
            for (int t = 0; t < 8; ++t) aw[t] = *(const bf16x8*)(bp + (size_t)t * 512);
            bf16x8 bx[2];
            #pragma unroll
            for (int mi = 0; mi < 2; ++mi) {
                int idx = ((mi * 16 + l4) * 64 + ksub * 32 + kg * 8) ^ ((l4 & 7) << 3);
                bx[mi] = *(const bf16x8*)&As[cur][idx];
            }
            __builtin_amdgcn_s_setprio(1);
            #pragma unroll
            for (int t = 0; t < 8; ++t)
                #pragma unroll
                for (int mi = 0; mi < 2; ++mi)
                    acc[mi][t] = __builtin_amdgcn_mfma_f32_16x16x32_bf16(aw[t], bx[mi], acc[mi][t], 0, 0, 0);
            __builtin_amdgcn_s_setprio(0);
        }
    }

    #pragma unroll
    for (int mi = 0; mi < 2; ++mi)
        #pragma unroll
        for (int t = 0; t < 8; ++t) {
            int n = wn * 128 + t * 16 + kg * 4;
            f32x4 b4 = *(const f32x4*)(bias + n);
            f32x4 v = acc[mi][t] + b4;
            *(f32x4*)(P + (size_t)(l0 + mi * 16 + l4) * DMODEL + n) = v;
        }
}

// main: out = nonsat(LN(x @ W1^T + P[m>>3]))
// 128 rows x 512 cols, 8 waves (2m x 4n), BK=32, grid 256 (1 block/CU).
// Deep async pipeline: global_load_lds for BOTH operands (zero VGPR cost,
// many loads in flight), counted s_waitcnt vmcnt(2) + raw s_barrier per
// k-step (loads stay in flight ACROSS barriers). W double-buffered (L2,
// dist 1); x fp32 triple-buffered (HBM, dist 2) with pre-swizzled global
// source so LDS dest stays linear and frag reads are ~4-way max.
__global__ __launch_bounds__(512) void main_fused(
    const float* __restrict__ x, const short* __restrict__ Wbf,
    const float* __restrict__ P, const float* __restrict__ gamma,
    const float* __restrict__ beta, float* __restrict__ out)
{
    __shared__ __align__(16) char smem[65536 + 49152 + 4096 + 8192]; // 124 KB
    short* Wl    = (short*)smem;                        // 2 x 16384 shorts
    float* Xs    = (float*)(smem + 65536);              // 3 x 4096 floats
    float* P_lds = (float*)smem;                        // alias (post-loop)
    float* GBp   = (float*)(smem + 65536 + 49152);      // 1024 floats
    float* redp  = (float*)(smem + 65536 + 49152 + 4096); // 4*128*2 floats

    const int tid  = threadIdx.x;
    const int wid  = tid >> 6;
    const int wm   = wid >> 2;          // 0..1
    const int wn   = wid & 3;           // 0..3
    const int lane = tid & 63;
    const int l4   = lane & 15;
    const int kg   = lane >> 4;
    const int m0   = blockIdx.x * 128;
    const int l0   = m0 >> 3;

    f32x4 acc[4][8];
    #pragma unroll
    for (int mi = 0; mi < 4; ++mi)
        #pragma unroll
        for (int t = 0; t < 8; ++t) acc[mi][t] = (f32x4){0.f,0.f,0.f,0.f};

    // x staging slots: slot s (16B) -> row s>>3, chunk cc = s&7 holds
    // global chunk c = cc ^ ((row&3)<<1)  (write-side swizzle via source).
    const int xrow0 = tid >> 3;                 // rows tid/8 and +64
    const int xcc0  = tid & 7;

    #define ISSUE_W(kf, buf) do {                                           \
        const short* wg_ = Wbf + (size_t)(kf) * 16384;                      \
        _Pragma("unroll")                                                   \
        for (int i_ = 0; i_ < 4; ++i_)                                      \
            gll16(wg_ + (tid + i_ * 512) * 8,                               \
                  Wl + (size_t)(buf) * 16384 + (tid + i_ * 512) * 8);       \
    } while (0)

    #define ISSUE_X(kf, buf) do {                                           \
        _Pragma("unroll")                                                   \
        for (int i_ = 0; i_ < 2; ++i_) {                                    \
            int slot_ = tid + i_ * 512;                                     \
            int row_  = slot_ >> 3;                                         \
            int c_    = (slot_ & 7) ^ ((row_ & 3) << 1);                    \
            gll16(x + (size_t)(m0 + row_) * DMODEL + (kf) * 32 + c_ * 4,    \
                  Xs + (size_t)(buf) * 4096 + slot_ * 4);                   \
        }                                                                   \
    } while (0)

    // prologue: W(0), x(0), x(1)  -> 8 outstanding/wave
    ISSUE_W(0, 0);
    ISSUE_X(0, 0);
    ISSUE_X(1, 1);

    f32x4 pv[4], gb;

    #pragma unroll
    for (int kf = 0; kf < 16; ++kf) {
        if (kf == 15) { asm volatile("s_waitcnt vmcnt(0)" ::: "memory"); }
        else          { asm volatile("s_waitcnt vmcnt(2)" ::: "memory"); }
        __builtin_amdgcn_sched_barrier(0);
        __builtin_amdgcn_s_barrier();
        __builtin_amdgcn_sched_barrier(0);

        if (kf < 15) ISSUE_W(kf + 1, (kf + 1) & 1);
        if (kf < 14) ISSUE_X(kf + 2, (kf + 2) % 3);
        __builtin_amdgcn_sched_barrier(0);

        if (kf == 13) {
            const float* Pg = P + (size_t)l0 * DMODEL;
            #pragma unroll
            for (int i = 0; i < 4; ++i) pv[i] = *(const f32x4*)(Pg + i * 2048 + tid * 4);
            if (tid < 256) {
                const float* gsrc = (tid < 128) ? (gamma + tid * 4) : (beta + (tid - 128) * 4);
                gb = *(const f32x4*)gsrc;
            }
        }

        // W fragments (linear 1KB frag reads)
        const short* wl = Wl + (size_t)(kf & 1) * 16384;
        bf16x8 aw[8];
        #pragma unroll
        for (int t = 0; t < 8; ++t)
            aw[t] = *(const bf16x8*)(wl + (wn * 8 + t) * 512 + lane * 8);

        // x fragments: fp32 swizzled reads + in-register cvt
        const float* xs = Xs + (size_t)(kf % 3) * 4096;
        bf16x8 bx[4];
        #pragma unroll
        for (int mi = 0; mi < 4; ++mi) {
            int row = wm * 64 + mi * 16 + l4;
            const float* xb = xs + row * 32;
            f32x4 lo = *(const f32x4*)(xb + (((kg * 2 + 0) ^ ((row & 3) << 1)) << 2));
            f32x4 hi = *(const f32x4*)(xb + (((kg * 2 + 1) ^ ((row & 3) << 1)) << 2));
            union { u32x4 u; bf16x8 s; } cv;
            cv.u[0] = cvt_pk2(lo[0], lo[1]); cv.u[1] = cvt_pk2(lo[2], lo[3]);
            cv.u[2] = cvt_pk2(hi[0], hi[1]); cv.u[3] = cvt_pk2(hi[2], hi[3]);
            bx[mi] = cv.s;
        }

        __builtin_amdgcn_s_setprio(1);
        #pragma unroll
        for (int t = 0; t < 8; ++t)
            #pragma unroll
            for (int mi = 0; mi < 4; ++mi)
                acc[mi][t] = __builtin_amdgcn_mfma_f32_16x16x32_bf16(aw[t], bx[mi], acc[mi][t], 0, 0, 0);
        __builtin_amdgcn_s_setprio(0);
    }
    #undef ISSUE_W
    #undef ISSUE_X

    __syncthreads();   // full drain; Wl buffer now reusable as P_lds

    // ---- stage P (flat) + gamma/beta to LDS ----
    #pragma unroll
    for (int i = 0; i < 4; ++i) *(f32x4*)&P_lds[i * 2048 + tid * 4] = pv[i];
    if (tid < 256) {
        if (tid < 128) *(f32x4*)&GBp[tid * 4]                 = gb;
        else           *(f32x4*)&GBp[512 + (tid - 128) * 4]   = gb;
    }
    __syncthreads();

    // ---- add P (broadcast LDS reads) ----
    #pragma unroll
    for (int mi = 0; mi < 4; ++mi) {
        int lp = wm * 8 + mi * 2 + (l4 >> 3);
        #pragma unroll
        for (int t = 0; t < 8; ++t) {
            f32x4 p4 = *(const f32x4*)&P_lds[lp * 512 + wn * 128 + t * 16 + kg * 4];
            acc[mi][t] += p4;
        }
    }

    // ---- LN stats ----
    float S[4], Q[4];
    #pragma unroll
    for (int mi = 0; mi < 4; ++mi) {
        float s = 0.f, q = 0.f;
        #pragma unroll
        for (int t = 0; t < 8; ++t)
            #pragma unroll
            for (int j = 0; j < 4; ++j) {
                float v = acc[mi][t][j];
                s += v; q = __builtin_fmaf(v, v, q);
            }
        s += __shfl_xor(s, 16); q += __shfl_xor(q, 16);
        s += __shfl_xor(s, 32); q += __shfl_xor(q, 32);
        S[mi] = s; Q[mi] = q;
    }
    if (lane < 16) {
        #pragma unroll
        for (int mi = 0; mi < 4; ++mi) {
            int r = wm * 64 + mi * 16 + l4;
            redp[(wn * 128 + r) * 2 + 0] = S[mi];
            redp[(wn * 128 + r) * 2 + 1] = Q[mi];
        }
    }
    __syncthreads();

    // ---- normalize + nonsat + stores ----
    #pragma unroll
    for (int mi = 0; mi < 4; ++mi) {
        int r = wm * 64 + mi * 16 + l4;
        float Ss = 0.f, Qs = 0.f;
        #pragma unroll
        for (int w = 0; w < 4; ++w) {
            Ss += redp[(w * 128 + r) * 2 + 0];
            Qs += redp[(w * 128 + r) * 2 + 1];
        }
        float mean = Ss * (1.0f / 512.0f);
        float var  = Qs * (1.0f / 512.0f) - mean * mean;
        float rstd = rsqrtf(var + 1e-5f);
        float nmrs = -mean * rstd;
        float* orow = out + (size_t)(m0 + r) * DMODEL;
        #pragma unroll
        for (int t = 0; t < 8; ++t) {
            int n = wn * 128 + t * 16 + kg * 4;
            f32x4 g4 = *(const f32x4*)&GBp[n];
            f32x4 b4 = *(const f32x4*)&GBp[512 + n];
            f32x4 o;
            #pragma unroll
            for (int j = 0; j < 4; ++j) {
                float z = __builtin_fmaf(acc[mi][t][j], rstd, nmrs);
                float v = __builtin_fmaf(z, g4[j], b4[j]);
                o[j] = nonsat(v);
            }
            *(f32x4*)(orow + n) = o;
        }
    }
}

// ---------- fallback (no workspace) ----------
__global__ __launch_bounds__(256) void fallback_fwd(
    const float* __restrict__ x, const float* __restrict__ Wf,
    const float* __restrict__ bias, const float* __restrict__ gamma,
    const float* __restrict__ beta, const float* __restrict__ pe,
    float* __restrict__ out)
{
    const int tid  = threadIdx.x;
    const int wave = tid >> 6;
    const int lane = tid & 63;
    const int lrow = lane & 15;
    const int kgrp = lane >> 4;
    const int n0   = wave * 128;
    const int m0   = blockIdx.x * 32;

    f32x4 acc[2][8];
    #pragma unroll
    for (int a = 0; a < 2; ++a)
        #pragma unroll
        for (int t = 0; t < 8; ++t) acc[a][t] = (f32x4){0.f,0.f,0.f,0.f};

    const int mA[2] = { m0 + lrow, m0 + 16 + lrow };
    for (int ks = 0; ks < 32; ++ks) {
        const int kb = ks * 32 + kgrp * 8;
        bf16x8 afrag[2];
        #pragma unroll
        for (int a = 0; a < 2; ++a) {
            const float* src = (kb < 512)
                ? (x  + (size_t)mA[a] * 512 + kb)
                : (pe + (size_t)(mA[a] >> 3) * 512 + (kb - 512));
            f32x4 lo = *(const f32x4*)src;
            f32x4 hi = *(const f32x4*)(src + 4);
            union { u32x4 u; bf16x8 s; } cv;
            cv.u[0] = cvt_pk2(lo[0], lo[1]); cv.u[1] = cvt_pk2(lo[2], lo[3]);
            cv.u[2] = cvt_pk2(hi[0], hi[1]); cv.u[3] = cvt_pk2(hi[2], hi[3]);
            afrag[a] = cv.s;
        }
        #pragma unroll
        for (int t = 0; t < 8; ++t) {
            const int n = n0 + t * 16 + lrow;
            const float* wsrc = Wf + (size_t)n * KFULL + kb;
            f32x4 lo = *(const f32x4*)wsrc;
            f32x4 hi = *(const f32x4*)(wsrc + 4);
            union { u32x4 u; bf16x8 s; } cv;
            cv.u[0] = cvt_pk2(lo[0], lo[1]); cv.u[1] = cvt_pk2(lo[2], lo[3]);
            cv.u[2] = cvt_pk2(hi[0], hi[1]); cv.u[3] = cvt_pk2(hi[2], hi[3]);
            acc[0][t] = __builtin_amdgcn_mfma_f32_16x16x32_bf16(afrag[0], cv.s, acc[0][t], 0, 0, 0);
            acc[1][t] = __builtin_amdgcn_mfma_f32_16x16x32_bf16(afrag[1], cv.s, acc[1][t], 0, 0, 0);
        }
    }
    __shared__ float red[4][32][2];
    float bcol[8], gcol[8], ecol[8];
    #pragma unroll
    for (int t = 0; t < 8; ++t) {
        const int n = n0 + t * 16 + lrow;
        bcol[t] = bias[n]; gcol[t] = gamma[n]; ecol[t] = beta[n];
    }
    #pragma unroll
    for (int a = 0; a < 2; ++a)
        #pragma unroll
        for (int t = 0; t < 8; ++t)
            #pragma unroll
            for (int j = 0; j < 4; ++j) acc[a][t][j] += bcol[t];
    float sm[2][4], sq[2][4];
    #pragma unroll
    for (int a = 0; a < 2; ++a)
        #pragma unroll
        for (int j = 0; j < 4; ++j) {
            float s = 0.f, q = 0.f;
            #pragma unroll
            for (int t = 0; t < 8; ++t) { float v = acc[a][t][j]; s += v; q += v * v; }
            #pragma unroll
            for (int msk = 1; msk <= 8; msk <<= 1) {
                s += __shfl_xor(s, msk, 64);
                q += __shfl_xor(q, msk, 64);
            }
            sm[a][j] = s; sq[a][j] = q;
        }
    if (lrow == 0) {
        #pragma unroll
        for (int a = 0; a < 2; ++a)
            #pragma unroll
            for (int j = 0; j < 4; ++j) {
                int r = a * 16 + kgrp * 4 + j;
                red[wave][r][0] = sm[a][j];
                red[wave][r][1] = sq[a][j];
            }
    }
    __syncthreads();
    #pragma unroll
    for (int a = 0; a < 2; ++a)
        #pragma unroll
        for (int j = 0; j < 4; ++j) {
            const int r = a * 16 + kgrp * 4 + j;
            float Ss = red[0][r][0] + red[1][r][0] + red[2][r][0] + red[3][r][0];
            float Qs = red[0][r][1] + red[1][r][1] + red[2][r][1] + red[3][r][1];
            float mean = Ss * (1.0f / 512.0f);
            float var  = Qs * (1.0f / 512.0f) - mean * mean;
            float rstd = rsqrtf(var + 1e-5f);
            const int m = m0 + a * 16 + kgrp * 4 + j;
            float* orow = out + (size_t)m * 512;
            #pragma unroll
            for (int t = 0; t < 8; ++t) {
                const int n = n0 + t * 16 + lrow;
                float v = (acc[a][t][j] - mean) * rstd * gcol[t] + ecol[t];
                orow[n] = nonsat(v);
            }
        }
}

extern "C" void kernel_launch(void* const* d_in, const int* in_sizes, int n_in,
                              void* d_out, int out_size, void* d_ws, size_t ws_size,
                              hipStream_t stream) {
    const float* x     = (const float*)d_in[0];
    const float* W     = (const float*)d_in[1];
    const float* bias  = (const float*)d_in[2];
    const float* gamma = (const float*)d_in[3];
    const float* beta  = (const float*)d_in[4];
    const float* pe    = (const float*)d_in[5];
    float* out = (float*)d_out;

    const size_t WBF_BYTES = (size_t)KFULL * DMODEL * sizeof(short);   // 1 MB
    const size_t P_BYTES   = (size_t)SEQL * DMODEL * sizeof(float);    // 8 MB

    if (ws_size >= WBF_BYTES + P_BYTES) {
        short* Wbf = (short*)d_ws;
        float* P   = (float*)((char*)d_ws + WBF_BYTES);
        cvt_w<<<dim3((DMODEL * KFULL) / (256 * 8)), dim3(256), 0, stream>>>(W, Wbf);
        pe_gemm<<<dim3(SEQL / 32), dim3(256), 0, stream>>>(pe, Wbf, bias, P);
        main_fused<<<dim3(MROWS / 128), dim3(512), 0, stream>>>(x, Wbf, P, gamma, beta, out);
    } else {
        fallback_fwd<<<dim3(MROWS / 32), dim3(256), 0, stream>>>(x, W, bias, gamma, beta, pe, out);
    }
}

// Round 18
// 54.586 us; speedup vs baseline: 1.2438x; 1.1266x over previous
//
#include <hip/hip_runtime.h>
#include <hip/hip_bf16.h>

#define SEQL 4096
#define MROWS 32768
#define DMODEL 512
#define KFULL 1024

typedef __attribute__((ext_vector_type(8))) short bf16x8;
typedef __attribute__((ext_vector_type(4))) unsigned u32x4;
typedef __attribute__((ext_vector_type(4))) float f32x4;

__device__ __forceinline__ unsigned cvt_pk2(float a, float b) {
    unsigned r;
    asm("v_cvt_pk_bf16_f32 %0, %1, %2" : "=v"(r) : "v"(a), "v"(b));
    return r;
}

__device__ __forceinline__ float nonsat(float x) {
    float y = x;
    #pragma unroll
    for (int i = 0; i < 5; ++i) {
        float y2  = y * y;
        float num = __builtin_fmaf(y2 * y, 0.66666667f, x);
        y = num * __builtin_amdgcn_rcpf(y2 + 1.0f);
    }
    return y;
}

// W (512x1024 f32 [n][k]) -> fragment-tiled bf16:
// frag f = (k/32)*32 + (n/16); lane = ((k/8)&3)*16 + (n&15); elems k..k+7.
__global__ __launch_bounds__(256) void cvt_w(const float* __restrict__ W,
                                             short* __restrict__ Wbf) {
    int t8 = blockIdx.x * 256 + threadIdx.x;
    int n = t8 >> 7;
    int k = (t8 & 127) << 3;
    f32x4 lo = *(const f32x4*)(W + (size_t)n * KFULL + k);
    f32x4 hi = *(const f32x4*)(W + (size_t)n * KFULL + k + 4);
    u32x4 v;
    v[0] = cvt_pk2(lo[0], lo[1]); v[1] = cvt_pk2(lo[2], lo[3]);
    v[2] = cvt_pk2(hi[0], hi[1]); v[3] = cvt_pk2(hi[2], hi[3]);
    int f    = (k >> 5) * 32 + (n >> 4);
    int lane = ((k >> 3) & 3) * 16 + (n & 15);
    *(u32x4*)(Wbf + (size_t)f * 512 + lane * 8) = v;
}

// main (fully fused): out = nonsat(LN(x @ W1^T + (pe @ W2^T + bias)[m>>3]))
// 128 rows x 512 cols per block, 8 waves (2m x 4n), BK=32, grid 256 (1/CU).
// Phase 0 (in-kernel pe-GEMM): each block's 16 P-rows are block-exclusive;
//   wave w computes cols w*64..w*64+64 over K=512 (W2 frags from L2, pe
//   B-frags from global, barrier-free) -> P_lds[16][512] (+bias).
// Phase 1: r15's verified K-loop — double-buffered LDS W (frag layout,
//   flat copy) + x (frag layout, write-side permutation), 1 barrier/k-step.
__global__ __launch_bounds__(512, 2) void main_fused(
    const float* __restrict__ x, const short* __restrict__ Wbf,
    const float* __restrict__ pe, const float* __restrict__ bias,
    const float* __restrict__ gamma, const float* __restrict__ beta,
    float* __restrict__ out)
{
    __shared__ __align__(16) short Wl[2][16384];   // 64 KB
    __shared__ __align__(16) short As[2][4096];    // 16 KB
    __shared__ float P_lds[16 * 512];              // 32 KB
    __shared__ float GB[2][512];                   // 4 KB
    __shared__ float red[4][128][2];               // 4 KB  -> 120 KB total

    const int tid  = threadIdx.x;
    const int wid  = tid >> 6;
    const int wm   = wid >> 2;
    const int wn   = wid & 3;
    const int lane = tid & 63;
    const int l4   = lane & 15;
    const int kg   = lane >> 4;
    const int m0   = blockIdx.x * 128;
    const int l0   = m0 >> 3;           // 16 exclusive P rows per block

    // ================= Phase 0: in-kernel pe-GEMM -> P_lds ================
    {
        f32x4 accp[4];
        #pragma unroll
        for (int t = 0; t < 4; ++t) accp[t] = (f32x4){0.f, 0.f, 0.f, 0.f};
        // pe B-frag source: lane (l4,kg) holds pe[l0+l4][k + kg*8 .. +8]
        const float* peb = pe + (size_t)(l0 + l4) * DMODEL + kg * 8;
        #pragma unroll
        for (int kf = 0; kf < 16; ++kf) {
            f32x4 lo = *(const f32x4*)(peb + kf * 32);
            f32x4 hi = *(const f32x4*)(peb + kf * 32 + 4);
            union { u32x4 u; bf16x8 s; } cv;
            cv.u[0] = cvt_pk2(lo[0], lo[1]); cv.u[1] = cvt_pk2(lo[2], lo[3]);
            cv.u[2] = cvt_pk2(hi[0], hi[1]); cv.u[3] = cvt_pk2(hi[2], hi[3]);
            bf16x8 bpe = cv.s;
            #pragma unroll
            for (int t = 0; t < 4; ++t) {
                // W2 frag: f = (16+kf)*32 + (wave's n-frag = wid*4 + t)
                const short* ap = Wbf + (size_t)((16 + kf) * 32 + wid * 4 + t) * 512 + lane * 8;
                bf16x8 aw2 = *(const bf16x8*)ap;
                accp[t] = __builtin_amdgcn_mfma_f32_16x16x32_bf16(aw2, bpe, accp[t], 0, 0, 0);
            }
        }
        // C layout: col(l4) = pe row l, row(kg*4+j) = n within frag
        #pragma unroll
        for (int t = 0; t < 4; ++t) {
            int n = wid * 64 + t * 16 + kg * 4;
            f32x4 b4 = *(const f32x4*)(bias + n);
            *(f32x4*)&P_lds[l4 * 512 + n] = accp[t] + b4;
        }
    }
    // P_lds reads happen in the epilogue, after many __syncthreads.

    // ================= Phase 1: main GEMM (r15 skeleton) ===================
    f32x4 acc[4][8];
    #pragma unroll
    for (int mi = 0; mi < 4; ++mi)
        #pragma unroll
        for (int t = 0; t < 8; ++t) acc[mi][t] = (f32x4){0.f,0.f,0.f,0.f};

    // x: thread -> row tid/4, k-chunk (tid&3)*8 (8 fp32 = 32B, coalesced)
    const float* xp = x + (size_t)(m0 + (tid >> 2)) * DMODEL + (tid & 3) * 8;
    // As frag-layout write address (shorts): frag = row/16 (== wid here),
    // lane = (k/8)*16 + row%16
    const int as_adr = wid * 512 + ((tid & 3) * 16 + ((tid >> 2) & 15)) * 8;

    u32x4 wr[4];
    f32x4 xr0, xr1;

    #define LOADS(kf)  do {                                                     \
        const short* wg = Wbf + (size_t)(kf) * 16384 + tid * 8;                 \
        wr[0] = *(const u32x4*)(wg);                                            \
        wr[1] = *(const u32x4*)(wg + 4096);                                     \
        wr[2] = *(const u32x4*)(wg + 8192);                                     \
        wr[3] = *(const u32x4*)(wg + 12288);                                    \
        xr0 = *(const f32x4*)(xp + (kf) * 32);                                  \
        xr1 = *(const f32x4*)(xp + (kf) * 32 + 4);                              \
    } while (0)

    #define WRITES(b)  do {                                                     \
        *(u32x4*)&Wl[b][tid * 8]         = wr[0];                               \
        *(u32x4*)&Wl[b][tid * 8 + 4096]  = wr[1];                               \
        *(u32x4*)&Wl[b][tid * 8 + 8192]  = wr[2];                               \
        *(u32x4*)&Wl[b][tid * 8 + 12288] = wr[3];                               \
        u32x4 v;                                                                \
        v[0] = cvt_pk2(xr0[0], xr0[1]); v[1] = cvt_pk2(xr0[2], xr0[3]);         \
        v[2] = cvt_pk2(xr1[0], xr1[1]); v[3] = cvt_pk2(xr1[2], xr1[3]);         \
        *(u32x4*)&As[b][as_adr] = v;                                            \
    } while (0)

    LOADS(0);
    WRITES(0);
    LOADS(1);

    f32x4 gb;

    #pragma unroll
    for (int kf = 0; kf < 16; ++kf) {
        const int cur = kf & 1;
        __syncthreads();
        if (kf < 15) WRITES(cur ^ 1);
        if (kf < 14) LOADS(kf + 2);
        if (kf == 13) {
            if (tid < 256) {
                const float* gsrc = (tid < 128) ? (gamma + tid * 4) : (beta + (tid - 128) * 4);
                gb = *(const f32x4*)gsrc;
            }
        }
        bf16x8 aw[8];
        #pragma unroll
        for (int t = 0; t < 8; ++t)
            aw[t] = *(const bf16x8*)&Wl[cur][(wn * 8 + t) * 512 + lane * 8];
        bf16x8 bx[4];
        #pragma unroll
        for (int mi = 0; mi < 4; ++mi)
            bx[mi] = *(const bf16x8*)&As[cur][(wm * 4 + mi) * 512 + lane * 8];
        __builtin_amdgcn_s_setprio(1);
        #pragma unroll
        for (int t = 0; t < 8; ++t)
            #pragma unroll
            for (int mi = 0; mi < 4; ++mi)
                acc[mi][t] = __builtin_amdgcn_mfma_f32_16x16x32_bf16(aw[t], bx[mi], acc[mi][t], 0, 0, 0);
        __builtin_amdgcn_s_setprio(0);
    }
    #undef LOADS
    #undef WRITES

    // ---- stage gamma/beta to LDS (P already resident in P_lds) ----
    if (tid < 256) {
        if (tid < 128) *(f32x4*)&GB[0][tid * 4]         = gb;
        else           *(f32x4*)&GB[1][(tid - 128) * 4] = gb;
    }
    __syncthreads();

    // ---- add P (broadcast LDS reads) ----
    #pragma unroll
    for (int mi = 0; mi < 4; ++mi) {
        int lp = wm * 8 + mi * 2 + (l4 >> 3);
        #pragma unroll
        for (int t = 0; t < 8; ++t) {
            f32x4 p4 = *(const f32x4*)&P_lds[lp * 512 + wn * 128 + t * 16 + kg * 4];
            acc[mi][t] += p4;
        }
    }

    // ---- LN stats ----
    float S[4], Q[4];
    #pragma unroll
    for (int mi = 0; mi < 4; ++mi) {
        float s = 0.f, q = 0.f;
        #pragma unroll
        for (int t = 0; t < 8; ++t)
            #pragma unroll
            for (int j = 0; j < 4; ++j) {
                float v = acc[mi][t][j];
                s += v; q = __builtin_fmaf(v, v, q);
            }
        s += __shfl_xor(s, 16); q += __shfl_xor(q, 16);
        s += __shfl_xor(s, 32); q += __shfl_xor(q, 32);
        S[mi] = s; Q[mi] = q;
    }
    if (lane < 16) {
        #pragma unroll
        for (int mi = 0; mi < 4; ++mi) {
            red[wn][wm * 64 + mi * 16 + l4][0] = S[mi];
            red[wn][wm * 64 + mi * 16 + l4][1] = Q[mi];
        }
    }
    __syncthreads();

    // ---- normalize + nonsat + stores ----
    #pragma unroll
    for (int mi = 0; mi < 4; ++mi) {
        int r = wm * 64 + mi * 16 + l4;
        float Ss = red[0][r][0] + red[1][r][0] + red[2][r][0] + red[3][r][0];
        float Qs = red[0][r][1] + red[1][r][1] + red[2][r][1] + red[3][r][1];
        float mean = Ss * (1.0f / 512.0f);
        float var  = Qs * (1.0f / 512.0f) - mean * mean;
        float rstd = rsqrtf(var + 1e-5f);
        float nmrs = -mean * rstd;
        float* orow = out + (size_t)(m0 + r) * DMODEL;
        #pragma unroll
        for (int t = 0; t < 8; ++t) {
            int n = wn * 128 + t * 16 + kg * 4;
            f32x4 g4 = *(const f32x4*)&GB[0][n];
            f32x4 b4 = *(const f32x4*)&GB[1][n];
            f32x4 o;
            #pragma unroll
            for (int j = 0; j < 4; ++j) {
                float z = __builtin_fmaf(acc[mi][t][j], rstd, nmrs);
                float v = __builtin_fmaf(z, g4[j], b4[j]);
                o[j] = nonsat(v);
            }
            *(f32x4*)(orow + n) = o;
        }
    }
}

// ---------- fallback (no workspace) ----------
__global__ __launch_bounds__(256) void fallback_fwd(
    const float* __restrict__ x, const float* __restrict__ Wf,
    const float* __restrict__ bias, const float* __restrict__ gamma,
    const float* __restrict__ beta, const float* __restrict__ pe,
    float* __restrict__ out)
{
    const int tid  = threadIdx.x;
    const int wave = tid >> 6;
    const int lane = tid & 63;
    const int lrow = lane & 15;
    const int kgrp = lane >> 4;
    const int n0   = wave * 128;
    const int m0   = blockIdx.x * 32;

    f32x4 acc[2][8];
    #pragma unroll
    for (int a = 0; a < 2; ++a)
        #pragma unroll
        for (int t = 0; t < 8; ++t) acc[a][t] = (f32x4){0.f,0.f,0.f,0.f};

    const int mA[2] = { m0 + lrow, m0 + 16 + lrow };
    for (int ks = 0; ks < 32; ++ks) {
        const int kb = ks * 32 + kgrp * 8;
        bf16x8 afrag[2];
        #pragma unroll
        for (int a = 0; a < 2; ++a) {
            const float* src = (kb < 512)
                ? (x  + (size_t)mA[a] * 512 + kb)
                : (pe + (size_t)(mA[a] >> 3) * 512 + (kb - 512));
            f32x4 lo = *(const f32x4*)src;
            f32x4 hi = *(const f32x4*)(src + 4);
            union { u32x4 u; bf16x8 s; } cv;
            cv.u[0] = cvt_pk2(lo[0], lo[1]); cv.u[1] = cvt_pk2(lo[2], lo[3]);
            cv.u[2] = cvt_pk2(hi[0], hi[1]); cv.u[3] = cvt_pk2(hi[2], hi[3]);
            afrag[a] = cv.s;
        }
        #pragma unroll
        for (int t = 0; t < 8; ++t) {
            const int n = n0 + t * 16 + lrow;
            const float* wsrc = Wf + (size_t)n * KFULL + kb;
            f32x4 lo = *(const f32x4*)wsrc;
            f32x4 hi = *(const f32x4*)(wsrc + 4);
            union { u32x4 u; bf16x8 s; } cv;
            cv.u[0] = cvt_pk2(lo[0], lo[1]); cv.u[1] = cvt_pk2(lo[2], lo[3]);
            cv.u[2] = cvt_pk2(hi[0], hi[1]); cv.u[3] = cvt_pk2(hi[2], hi[3]);
            acc[0][t] = __builtin_amdgcn_mfma_f32_16x16x32_bf16(afrag[0], cv.s, acc[0][t], 0, 0, 0);
            acc[1][t] = __builtin_amdgcn_mfma_f32_16x16x32_bf16(afrag[1], cv.s, acc[1][t], 0, 0, 0);
        }
    }
    __shared__ float red[4][32][2];
    float bcol[8], gcol[8], ecol[8];
    #pragma unroll
    for (int t = 0; t < 8; ++t) {
        const int n = n0 + t * 16 + lrow;
        bcol[t] = bias[n]; gcol[t] = gamma[n]; ecol[t] = beta[n];
    }
    #pragma unroll
    for (int a = 0; a < 2; ++a)
        #pragma unroll
        for (int t = 0; t < 8; ++t)
            #pragma unroll
            for (int j = 0; j < 4; ++j) acc[a][t][j] += bcol[t];
    float sm[2][4], sq[2][4];
    #pragma unroll
    for (int a = 0; a < 2; ++a)
        #pragma unroll
        for (int j = 0; j < 4; ++j) {
            float s = 0.f, q = 0.f;
            #pragma unroll
            for (int t = 0; t < 8; ++t) { float v = acc[a][t][j]; s += v; q += v * v; }
            #pragma unroll
            for (int msk = 1; msk <= 8; msk <<= 1) {
                s += __shfl_xor(s, msk, 64);
                q += __shfl_xor(q, msk, 64);
            }
            sm[a][j] = s; sq[a][j] = q;
        }
    if (lrow == 0) {
        #pragma unroll
        for (int a = 0; a < 2; ++a)
            #pragma unroll
            for (int j = 0; j < 4; ++j) {
                int r = a * 16 + kgrp * 4 + j;
                red[wave][r][0] = sm[a][j];
                red[wave][r][1] = sq[a][j];
            }
    }
    __syncthreads();
    #pragma unroll
    for (int a = 0; a < 2; ++a)
        #pragma unroll
        for (int j = 0; j < 4; ++j) {
            const int r = a * 16 + kgrp * 4 + j;
            float Ss = red[0][r][0] + red[1][r][0] + red[2][r][0] + red[3][r][0];
            float Qs = red[0][r][1] + red[1][r][1] + red[2][r][1] + red[3][r][1];
            float mean = Ss * (1.0f / 512.0f);
            float var  = Qs * (1.0f / 512.0f) - mean * mean;
            float rstd = rsqrtf(var + 1e-5f);
            const int m = m0 + a * 16 + kgrp * 4 + j;
            float* orow = out + (size_t)m * 512;
            #pragma unroll
            for (int t = 0; t < 8; ++t) {
                const int n = n0 + t * 16 + lrow;
                float v = (acc[a][t][j] - mean) * rstd * gcol[t] + ecol[t];
                orow[n] = nonsat(v);
            }
        }
}

extern "C" void kernel_launch(void* const* d_in, const int* in_sizes, int n_in,
                              void* d_out, int out_size, void* d_ws, size_t ws_size,
                              hipStream_t stream) {
    const float* x     = (const float*)d_in[0];
    const float* W     = (const float*)d_in[1];
    const float* bias  = (const float*)d_in[2];
    const float* gamma = (const float*)d_in[3];
    const float* beta  = (const float*)d_in[4];
    const float* pe    = (const float*)d_in[5];
    float* out = (float*)d_out;

    const size_t WBF_BYTES = (size_t)KFULL * DMODEL * sizeof(short);   // 1 MB

    if (ws_size >= WBF_BYTES) {
        short* Wbf = (short*)d_ws;
        cvt_w<<<dim3((DMODEL * KFULL) / (256 * 8)), dim3(256), 0, stream>>>(W, Wbf);
        main_fused<<<dim3(MROWS / 128), dim3(512), 0, stream>>>(x, Wbf, pe, bias, gamma, beta, out);
    } else {
        fallback_fwd<<<dim3(MROWS / 32), dim3(256), 0, stream>>>(x, W, bias, gamma, beta, pe, out);
    }
}